// Round 9
// baseline (56.457 us; speedup 1.0000x reference)
//
#include <hip/hip_runtime.h>

// PatchManifold: bilinear 10x downsample (align_corners=False, scale 10 ->
// frac == 0.5 exactly -> resized pixel = mean of 2x2 input block at rows
// 10i+4,10i+5 / cols 10j+4,10j+5), 16x16 pairwise patch affinity
// mean_d(exp(-(Pa-Pb)^2)), diag == 1, zero 2 smallest per row (stable
// first-index tie-break == jnp.argsort take-k).
//
// Input : d_in[0] = targets f32 [8,3,2560,2560]
// Output: d_out   = f32 [16,16]
//
// R8 -> R9: ONE change. K1 becomes persistent + software-pipelined:
// 2048 blocks (8/CU exactly, 20KB LDS), each owns 3 consecutive 20KB
// chunks; chunk g+1 is prefetched into registers (5x float4) while chunk g
// is extracted from LDS -> HBM latency hides under extract/write, no block
// relaunch between generations. (R8's 6144 short blocks left the per-block
// tail on the critical path; K1 ran ~5 TB/s vs the 6.5 TB/s fill rate.)
//
// 3 dispatches:
//   K1 pm_resize_pipe <<<2048,256>>>: blocks 0..15 also zero the 16KB
//      shadow region. Per chunk: stream 20KB (rows 10i+4,10i+5 contiguous)
//      via LDS, write P_mat[16][98304].
//   K2 pm_pairs <<<768,256>>>: 2 threads/column (60 pairs each, template
//      fill keeps v[] in VGPRs - rule #20), 63-shfl transposed butterfly,
//      one f64 atomicAdd per thread-slot into 16 shadows. No fences.
//   K3 pm_finish <<<1,256>>>: sum shadows, mean, mirror, mask, write.

#define W_IN 2560
#define IMG_STRIDE (2560 * 2560)
#define D_TOTAL_I 98304
#define D_TOTAL 98304.0

#define NSHADOW 16
#define SLOT_STRIDE 128
#define SHADOW_BYTES (NSHADOW * SLOT_STRIDE * 8)   // 16 KiB
#define PMAT_OFF 65536
#define WS_NEEDED (PMAT_OFF + 16 * D_TOTAL_I * 4)

// ============================ K1: persistent pipelined resize ============================

__global__ __launch_bounds__(256) void pm_resize_pipe(const float* __restrict__ in,
                                                      float* __restrict__ Pm,
                                                      unsigned int* __restrict__ wsu) {
    const int blk = blockIdx.x;            // 0..2047; chunks 3*blk .. 3*blk+2
    const int tid = threadIdx.x;

    // zero the 16KB shadow region (kernel boundary orders it before K2)
    if (blk < 16) wsu[blk * 256 + tid] = 0u;

    __shared__ float rows[2 * W_IN];       // 20 KB -> 8 blocks/CU

    float4 reg[5];
    {   // prefetch chunk 0
        const int c = blk * 3;
        const int i = c & 255, img = c >> 8;
        const float4* s4 = reinterpret_cast<const float4*>(
            in + (size_t)img * IMG_STRIDE + (size_t)(10 * i + 4) * W_IN);
#pragma unroll
        for (int q = 0; q < 5; ++q) reg[q] = s4[q * 256 + tid];
    }

#pragma unroll
    for (int g = 0; g < 3; ++g) {
        // regs (chunk g) -> LDS
        float4* l4 = reinterpret_cast<float4*>(rows);
#pragma unroll
        for (int q = 0; q < 5; ++q) l4[q * 256 + tid] = reg[q];
        __syncthreads();

        // issue chunk g+1 loads (latency hides under extract+write below)
        if (g < 2) {
            const int c = blk * 3 + g + 1;
            const int i = c & 255, img = c >> 8;
            const float4* s4 = reinterpret_cast<const float4*>(
                in + (size_t)img * IMG_STRIDE + (size_t)(10 * i + 4) * W_IN);
#pragma unroll
            for (int q = 0; q < 5; ++q) reg[q] = s4[q * 256 + tid];
        }

        // extract chunk g from LDS: thread = output col j, 2x2 average
        {
            const int c = blk * 3 + g;
            const int i = c & 255, img = c >> 8;
            const int j = tid;
            float a = rows[10 * j + 4],        b = rows[10 * j + 5];
            float e = rows[W_IN + 10 * j + 4], f = rows[W_IN + 10 * j + 5];
            const int n = i >> 6, hh = i & 63;
            const int m = j >> 6, ww = j & 63;
            Pm[(size_t)(n * 4 + m) * D_TOTAL_I + img * 4096 + hh * 64 + ww] =
                0.25f * ((a + b) + (e + f));
        }
        if (g < 2) __syncthreads();    // all LDS reads done before next store
    }
}

// ============================ K2: pairs ============================

// Compile-time HALF keeps every v[] index constant -> v stays in VGPRs.
template <int HALF>
__device__ __forceinline__ void pm_fill(const float* __restrict__ P,
                                        float* __restrict__ v) {
    int k = 0;
#pragma unroll
    for (int a = 0; a < 16; ++a)
#pragma unroll
        for (int b = a + 1; b < 16; ++b) {
            if (k >= HALF * 60 && k < HALF * 60 + 60) {
                float df = P[a] - P[b];
                v[k - HALF * 60] = __expf(-df * df);
            }
            ++k;
        }
}

__global__ __launch_bounds__(256) void pm_pairs(const float* __restrict__ Pm,
                                                double* __restrict__ acc) {
    const int tid  = threadIdx.x;
    const int lane = tid & 63;
    const int half = tid >> 7;                 // waves 0-1: pairs 0..59, 2-3: 60..119
    const int d    = blockIdx.x * 128 + (tid & 127);

    float P[16];
#pragma unroll
    for (int p = 0; p < 16; ++p) P[p] = Pm[p * D_TOTAL_I + d];

    float v[64];
    if (half == 0) pm_fill<0>(P, v);           // wave-uniform branch
    else           pm_fill<1>(P, v);
    v[60] = 0.0f; v[61] = 0.0f; v[62] = 0.0f; v[63] = 0.0f;

    // 6-stage transposed butterfly: lane ends owning slot bitrev6(lane),
    // fully wave-summed (verified R3/R7/R8).
#define PM_STAGE(K, H)                                         \
    {                                                          \
        const bool bit = (lane >> (K)) & 1;                    \
        _Pragma("unroll")                                      \
        for (int i = 0; i < (H); ++i) {                        \
            float keep = bit ? v[i + (H)] : v[i];              \
            float send = bit ? v[i] : v[i + (H)];              \
            v[i] = keep + __shfl_xor(send, 1 << (K), 64);      \
        }                                                      \
    }
    PM_STAGE(0, 32)
    PM_STAGE(1, 16)
    PM_STAGE(2, 8)
    PM_STAGE(3, 4)
    PM_STAGE(4, 2)
    PM_STAGE(5, 1)
#undef PM_STAGE

    const int r = __brev(lane) >> 26;
    double* shadow = acc + (size_t)(blockIdx.x & (NSHADOW - 1)) * SLOT_STRIDE;
    if (r < 60) atomicAdd(&shadow[half * 64 + r], (double)v[0]);
}

// ============================ K3: finish ============================

__global__ __launch_bounds__(256) void pm_finish(const double* __restrict__ acc,
                                                 float* __restrict__ out) {
    __shared__ float aff[256];
    const int tid = threadIdx.x;
    const int a = tid >> 4, b = tid & 15;
    if (a < b) {
        const int k = 15 * a - (a * (a - 1)) / 2 + (b - a - 1);  // pair idx
        const int slot = (k < 60) ? k : k + 4;                   // half1 at 64+
        double s = 0.0;
#pragma unroll
        for (int c = 0; c < NSHADOW; ++c) s += acc[c * SLOT_STRIDE + slot];
        float vv = (float)(s * (1.0 / D_TOTAL));
        aff[a * 16 + b] = vv;
        aff[b * 16 + a] = vv;
    } else if (a == b) {
        aff[tid] = 1.0f;             // mean(exp(0)) == 1 exactly
    }
    __syncthreads();
    if (tid < 16) {
        const float* row = &aff[tid * 16];
        float v1 = 1e30f; int i1 = -1;
        for (int j = 0; j < 16; ++j) {
            float x = row[j];
            if (x < v1) { v1 = x; i1 = j; }
        }
        float v2 = 1e30f; int i2 = -1;
        for (int j = 0; j < 16; ++j) {
            if (j == i1) continue;
            float x = row[j];
            if (x < v2) { v2 = x; i2 = j; }
        }
        for (int j = 0; j < 16; ++j)
            out[tid * 16 + j] = (j == i1 || j == i2) ? 0.0f : row[j];
    }
}

// ============================ fallback (round-1, verified) ============================

#define NPAIR_SLOTS_FB 256
#define NSHADOW_FB 8

__global__ __launch_bounds__(64) void pm_accum_fb(const float* __restrict__ in,
                                                  double* __restrict__ acc) {
    const int blk = blockIdx.x;
    const int hh  = blk & 63;
    const int img = blk >> 6;
    const int ww  = threadIdx.x;

    const float* base = in + (size_t)img * IMG_STRIDE;
    float P[16];
#pragma unroll
    for (int n = 0; n < 4; ++n) {
        const float* r0 = base + (size_t)(10 * (n * 64 + hh) + 4) * W_IN;
#pragma unroll
        for (int m = 0; m < 4; ++m) {
            const int col = 10 * (m * 64 + ww) + 4;
            float2 t = *reinterpret_cast<const float2*>(r0 + col);
            float2 u = *reinterpret_cast<const float2*>(r0 + W_IN + col);
            P[n * 4 + m] = 0.25f * ((t.x + t.y) + (u.x + u.y));
        }
    }
    double* shadow = acc + (size_t)(blk & (NSHADOW_FB - 1)) * NPAIR_SLOTS_FB;
    int k = 0;
#pragma unroll
    for (int a = 0; a < 16; ++a)
#pragma unroll
        for (int b = a + 1; b < 16; ++b) {
            float dd = P[a] - P[b];
            float vv = __expf(-dd * dd);
#pragma unroll
            for (int s = 32; s >= 1; s >>= 1) vv += __shfl_xor(vv, s, 64);
            if (ww == (k & 63)) atomicAdd(&shadow[a * 16 + b], (double)vv);
            ++k;
        }
}

__global__ __launch_bounds__(256) void pm_finish_fb(const double* __restrict__ acc,
                                                    float* __restrict__ out) {
    __shared__ float aff[256];
    const int tid = threadIdx.x;
    const int a = tid >> 4, b = tid & 15;
    if (a < b) {
        double s = 0.0;
#pragma unroll
        for (int c = 0; c < NSHADOW_FB; ++c) s += acc[c * NPAIR_SLOTS_FB + tid];
        float vv = (float)(s * (1.0 / D_TOTAL));
        aff[a * 16 + b] = vv;
        aff[b * 16 + a] = vv;
    } else if (a == b) {
        aff[tid] = 1.0f;
    }
    __syncthreads();
    if (tid < 16) {
        const float* row = &aff[tid * 16];
        float v1 = 1e30f; int i1 = -1;
        for (int j = 0; j < 16; ++j) {
            float x = row[j];
            if (x < v1) { v1 = x; i1 = j; }
        }
        float v2 = 1e30f; int i2 = -1;
        for (int j = 0; j < 16; ++j) {
            if (j == i1) continue;
            float x = row[j];
            if (x < v2) { v2 = x; i2 = j; }
        }
        for (int j = 0; j < 16; ++j)
            out[tid * 16 + j] = (j == i1 || j == i2) ? 0.0f : row[j];
    }
}

// ============================ launch ============================

extern "C" void kernel_launch(void* const* d_in, const int* in_sizes, int n_in,
                              void* d_out, int out_size, void* d_ws, size_t ws_size,
                              hipStream_t stream) {
    const float* in = (const float*)d_in[0];
    float* out = (float*)d_out;

    if (ws_size >= (size_t)WS_NEEDED) {
        double* acc = (double*)d_ws;
        unsigned int* wsu = (unsigned int*)d_ws;
        float* Pm = (float*)((char*)d_ws + PMAT_OFF);
        pm_resize_pipe<<<dim3(2048), dim3(256), 0, stream>>>(in, Pm, wsu);
        pm_pairs<<<dim3(768), dim3(256), 0, stream>>>(Pm, acc);
        pm_finish<<<dim3(1), dim3(256), 0, stream>>>(acc, out);
    } else {
        double* acc = (double*)d_ws;
        hipMemsetAsync(d_ws, 0, NSHADOW_FB * NPAIR_SLOTS_FB * sizeof(double), stream);
        pm_accum_fb<<<dim3(1536), dim3(64), 0, stream>>>(in, acc);
        pm_finish_fb<<<dim3(1), dim3(256), 0, stream>>>(acc, out);
    }
}

// Round 10
// 32.661 us; speedup vs baseline: 1.7286x; 1.7286x over previous
//
#include <hip/hip_runtime.h>

// PatchManifold: bilinear 10x downsample (align_corners=False, scale 10 ->
// frac == 0.5 exactly -> resized pixel = mean of 2x2 input block at rows
// 10i+4,10i+5 / cols 10j+4,10j+5), 16x16 pairwise patch affinity
// mean_d(exp(-(Pa-Pb)^2)), diag == 1, zero 2 smallest per row (stable
// first-index tie-break == jnp.argsort take-k).
//
// Input : d_in[0] = targets f32 [8,3,2560,2560]
// Output: d_out   = f32 [16,16]
//
// R9 -> R10: revert the persistent pipeline (R9: 32.75 -> 56.5us; the
// per-generation vmcnt(0)+barrier serialized each block; R8's 6144 short
// blocks get overlap free from the block scheduler). ONE change vs R8:
// K1 stages via __builtin_amdgcn_global_load_lds (width 16) instead of
// the float4 register round-trip -- removes the VGPR hop + one wait stage
// (guide common-mistake #1). LDS layout is linear, wave-uniform base +
// lane*16, contiguous global source: exactly the supported DMA pattern.
//
// 3 dispatches:
//   K1 pm_resize_gl <<<6144,256>>>: blocks 0..15 also zero the 16KB shadow
//      region. Stream 20KB chunk (rows 10i+4,10i+5 contiguous) -> LDS via
//      global_load_lds, extract 256 cols, write P_mat[16][98304].
//   K2 pm_pairs <<<768,256>>>: 2 threads/column (60 pairs each, template
//      fill keeps v[] in VGPRs - rule #20), 63-shfl transposed butterfly,
//      one f64 atomicAdd per thread-slot into 16 shadows. No fences.
//   K3 pm_finish <<<1,256>>>: sum shadows, mean, mirror, mask, write.

#define W_IN 2560
#define IMG_STRIDE (2560 * 2560)
#define D_TOTAL_I 98304
#define D_TOTAL 98304.0

#define NSHADOW 16
#define SLOT_STRIDE 128
#define SHADOW_BYTES (NSHADOW * SLOT_STRIDE * 8)   // 16 KiB
#define PMAT_OFF 65536
#define WS_NEEDED (PMAT_OFF + 16 * D_TOTAL_I * 4)

// ============================ K1: DMA-staged resize ============================

__global__ __launch_bounds__(256) void pm_resize_gl(const float* __restrict__ in,
                                                    float* __restrict__ Pm,
                                                    unsigned int* __restrict__ wsu) {
    const int blk = blockIdx.x;            // img*256 + i   (6144 blocks)
    const int tid = threadIdx.x;

    // zero the 16KB shadow region (kernel boundary orders it before K2)
    if (blk < 16) wsu[blk * 256 + tid] = 0u;

    const int i    = blk & 255;            // resized row 0..255
    const int img  = blk >> 8;
    const int wave = tid >> 6;
    const int lane = tid & 63;

    // rows 10i+4 and 10i+5: one contiguous 20KB chunk -> LDS via DMA.
    // Each global_load_lds: 64 lanes x 16B = 1KB segment; 20 segments total,
    // wave w owns segments w*5+q. LDS dest = uniform base + lane*16 (HW).
    __shared__ float rows[2 * W_IN];
    const float* gbase = in + (size_t)img * IMG_STRIDE + (size_t)(10 * i + 4) * W_IN;
#pragma unroll
    for (int q = 0; q < 5; ++q) {
        const int seg = wave * 5 + q;                      // 0..19
        const float* gsrc = gbase + seg * 256 + lane * 4;  // per-lane, 16B each
        float* ldst = rows + seg * 256;                    // wave-uniform base
        __builtin_amdgcn_global_load_lds(
            (const __attribute__((address_space(1))) void*)gsrc,
            (__attribute__((address_space(3))) void*)ldst,
            16, 0, 0);
    }
    __syncthreads();   // compiler drains vmcnt(0) before s_barrier

    // thread = output col j: 2x2 average from LDS
    const int j = tid;
    float a = rows[10 * j + 4],        b = rows[10 * j + 5];
    float c = rows[W_IN + 10 * j + 4], d = rows[W_IN + 10 * j + 5];
    const int n = i >> 6, hh = i & 63;
    const int m = j >> 6, ww = j & 63;
    Pm[(size_t)(n * 4 + m) * D_TOTAL_I + img * 4096 + hh * 64 + ww] =
        0.25f * ((a + b) + (c + d));
}

// ============================ K2: pairs ============================

// Compile-time HALF keeps every v[] index constant -> v stays in VGPRs.
template <int HALF>
__device__ __forceinline__ void pm_fill(const float* __restrict__ P,
                                        float* __restrict__ v) {
    int k = 0;
#pragma unroll
    for (int a = 0; a < 16; ++a)
#pragma unroll
        for (int b = a + 1; b < 16; ++b) {
            if (k >= HALF * 60 && k < HALF * 60 + 60) {
                float df = P[a] - P[b];
                v[k - HALF * 60] = __expf(-df * df);
            }
            ++k;
        }
}

__global__ __launch_bounds__(256) void pm_pairs(const float* __restrict__ Pm,
                                                double* __restrict__ acc) {
    const int tid  = threadIdx.x;
    const int lane = tid & 63;
    const int half = tid >> 7;                 // waves 0-1: pairs 0..59, 2-3: 60..119
    const int d    = blockIdx.x * 128 + (tid & 127);

    float P[16];
#pragma unroll
    for (int p = 0; p < 16; ++p) P[p] = Pm[p * D_TOTAL_I + d];

    float v[64];
    if (half == 0) pm_fill<0>(P, v);           // wave-uniform branch
    else           pm_fill<1>(P, v);
    v[60] = 0.0f; v[61] = 0.0f; v[62] = 0.0f; v[63] = 0.0f;

    // 6-stage transposed butterfly: lane ends owning slot bitrev6(lane),
    // fully wave-summed (verified R3/R7/R8).
#define PM_STAGE(K, H)                                         \
    {                                                          \
        const bool bit = (lane >> (K)) & 1;                    \
        _Pragma("unroll")                                      \
        for (int i = 0; i < (H); ++i) {                        \
            float keep = bit ? v[i + (H)] : v[i];              \
            float send = bit ? v[i] : v[i + (H)];              \
            v[i] = keep + __shfl_xor(send, 1 << (K), 64);      \
        }                                                      \
    }
    PM_STAGE(0, 32)
    PM_STAGE(1, 16)
    PM_STAGE(2, 8)
    PM_STAGE(3, 4)
    PM_STAGE(4, 2)
    PM_STAGE(5, 1)
#undef PM_STAGE

    const int r = __brev(lane) >> 26;
    double* shadow = acc + (size_t)(blockIdx.x & (NSHADOW - 1)) * SLOT_STRIDE;
    if (r < 60) atomicAdd(&shadow[half * 64 + r], (double)v[0]);
}

// ============================ K3: finish ============================

__global__ __launch_bounds__(256) void pm_finish(const double* __restrict__ acc,
                                                 float* __restrict__ out) {
    __shared__ float aff[256];
    const int tid = threadIdx.x;
    const int a = tid >> 4, b = tid & 15;
    if (a < b) {
        const int k = 15 * a - (a * (a - 1)) / 2 + (b - a - 1);  // pair idx
        const int slot = (k < 60) ? k : k + 4;                   // half1 at 64+
        double s = 0.0;
#pragma unroll
        for (int c = 0; c < NSHADOW; ++c) s += acc[c * SLOT_STRIDE + slot];
        float vv = (float)(s * (1.0 / D_TOTAL));
        aff[a * 16 + b] = vv;
        aff[b * 16 + a] = vv;
    } else if (a == b) {
        aff[tid] = 1.0f;             // mean(exp(0)) == 1 exactly
    }
    __syncthreads();
    if (tid < 16) {
        const float* row = &aff[tid * 16];
        float v1 = 1e30f; int i1 = -1;
        for (int j = 0; j < 16; ++j) {
            float x = row[j];
            if (x < v1) { v1 = x; i1 = j; }
        }
        float v2 = 1e30f; int i2 = -1;
        for (int j = 0; j < 16; ++j) {
            if (j == i1) continue;
            float x = row[j];
            if (x < v2) { v2 = x; i2 = j; }
        }
        for (int j = 0; j < 16; ++j)
            out[tid * 16 + j] = (j == i1 || j == i2) ? 0.0f : row[j];
    }
}

// ============================ fallback (round-1, verified) ============================

#define NPAIR_SLOTS_FB 256
#define NSHADOW_FB 8

__global__ __launch_bounds__(64) void pm_accum_fb(const float* __restrict__ in,
                                                  double* __restrict__ acc) {
    const int blk = blockIdx.x;
    const int hh  = blk & 63;
    const int img = blk >> 6;
    const int ww  = threadIdx.x;

    const float* base = in + (size_t)img * IMG_STRIDE;
    float P[16];
#pragma unroll
    for (int n = 0; n < 4; ++n) {
        const float* r0 = base + (size_t)(10 * (n * 64 + hh) + 4) * W_IN;
#pragma unroll
        for (int m = 0; m < 4; ++m) {
            const int col = 10 * (m * 64 + ww) + 4;
            float2 t = *reinterpret_cast<const float2*>(r0 + col);
            float2 u = *reinterpret_cast<const float2*>(r0 + W_IN + col);
            P[n * 4 + m] = 0.25f * ((t.x + t.y) + (u.x + u.y));
        }
    }
    double* shadow = acc + (size_t)(blk & (NSHADOW_FB - 1)) * NPAIR_SLOTS_FB;
    int k = 0;
#pragma unroll
    for (int a = 0; a < 16; ++a)
#pragma unroll
        for (int b = a + 1; b < 16; ++b) {
            float dd = P[a] - P[b];
            float vv = __expf(-dd * dd);
#pragma unroll
            for (int s = 32; s >= 1; s >>= 1) vv += __shfl_xor(vv, s, 64);
            if (ww == (k & 63)) atomicAdd(&shadow[a * 16 + b], (double)vv);
            ++k;
        }
}

__global__ __launch_bounds__(256) void pm_finish_fb(const double* __restrict__ acc,
                                                    float* __restrict__ out) {
    __shared__ float aff[256];
    const int tid = threadIdx.x;
    const int a = tid >> 4, b = tid & 15;
    if (a < b) {
        double s = 0.0;
#pragma unroll
        for (int c = 0; c < NSHADOW_FB; ++c) s += acc[c * NPAIR_SLOTS_FB + tid];
        float vv = (float)(s * (1.0 / D_TOTAL));
        aff[a * 16 + b] = vv;
        aff[b * 16 + a] = vv;
    } else if (a == b) {
        aff[tid] = 1.0f;
    }
    __syncthreads();
    if (tid < 16) {
        const float* row = &aff[tid * 16];
        float v1 = 1e30f; int i1 = -1;
        for (int j = 0; j < 16; ++j) {
            float x = row[j];
            if (x < v1) { v1 = x; i1 = j; }
        }
        float v2 = 1e30f; int i2 = -1;
        for (int j = 0; j < 16; ++j) {
            if (j == i1) continue;
            float x = row[j];
            if (x < v2) { v2 = x; i2 = j; }
        }
        for (int j = 0; j < 16; ++j)
            out[tid * 16 + j] = (j == i1 || j == i2) ? 0.0f : row[j];
    }
}

// ============================ launch ============================

extern "C" void kernel_launch(void* const* d_in, const int* in_sizes, int n_in,
                              void* d_out, int out_size, void* d_ws, size_t ws_size,
                              hipStream_t stream) {
    const float* in = (const float*)d_in[0];
    float* out = (float*)d_out;

    if (ws_size >= (size_t)WS_NEEDED) {
        double* acc = (double*)d_ws;
        unsigned int* wsu = (unsigned int*)d_ws;
        float* Pm = (float*)((char*)d_ws + PMAT_OFF);
        pm_resize_gl<<<dim3(6144), dim3(256), 0, stream>>>(in, Pm, wsu);
        pm_pairs<<<dim3(768), dim3(256), 0, stream>>>(Pm, acc);
        pm_finish<<<dim3(1), dim3(256), 0, stream>>>(acc, out);
    } else {
        double* acc = (double*)d_ws;
        hipMemsetAsync(d_ws, 0, NSHADOW_FB * NPAIR_SLOTS_FB * sizeof(double), stream);
        pm_accum_fb<<<dim3(1536), dim3(64), 0, stream>>>(in, acc);
        pm_finish_fb<<<dim3(1), dim3(256), 0, stream>>>(acc, out);
    }
}